// Round 7
// baseline (30.612 us; speedup 1.0000x reference)
//
#include <hip/hip_runtime.h>

// Edgenet: 4-channel fixed 3x3 Sobel-family stencil on [64,1,512,512] f32,
// edge = (sum_c |conv_c|) > 0 ? 1 : 0, output int32 [64,512,512].
//
// Round-7: BRANCH-FREE LOADS. Rounds 3/6 pinned at 4.6 TB/s with loads under
// branches (bounds check / divergent halo), which forces conservative
// s_waitcnt vmcnt(0) drains instead of counted waits. Now: clamp the row
// address to [0,511] and multiply the loaded row by a wave-uniform 0/1 mask
// -- every load is unconditional, vmcnt stays precisely counted. Window
// deepened to 6 slots (prefetch 4 rows ahead ~= 1000 cy slack > HBM latency).
// Wave owns a full 512-px strip (lane <-> 8 px), R=8 rows, no halo loads,
// regular int4 stores (nontemporal was a 4x regression in round 5).

#define IMG_W 512
#define IMG_H 512
#define R_ROWS 8
#define WSLOTS 6

struct Row {
  float4 lo, hi;   // pixels 8l..8l+3, 8l+4..8l+7
  float lft, rgt;  // halo pixels 8l-1, 8l+8
};

__device__ __forceinline__ float rget(const Row& r, int k) {
  switch (k) {   // k is compile-time constant after full unroll
    case 0: return r.lft;
    case 1: return r.lo.x; case 2: return r.lo.y;
    case 3: return r.lo.z; case 4: return r.lo.w;
    case 5: return r.hi.x; case 6: return r.hi.y;
    case 7: return r.hi.z; case 8: return r.hi.w;
    default: return r.rgt;
  }
}

// Unconditional, branch-free: clamped address; mask applied at finish.
__device__ __forceinline__ void loadrow(Row& r, const float* img, int yy, int px) {
  int yc = min(max(yy, 0), IMG_H - 1);
  const float* p = img + yc * IMG_W + px;
  r.lo = *reinterpret_cast<const float4*>(p);
  r.hi = *reinterpret_cast<const float4*>(p + 4);
}

__device__ __forceinline__ void finishrow(Row& r, int yy, int lane) {
  // counted vmcnt wait lands here at first use of loaded data
  float mask = ((unsigned)yy < (unsigned)IMG_H) ? 1.f : 0.f;  // wave-uniform
  r.lo.x *= mask; r.lo.y *= mask; r.lo.z *= mask; r.lo.w *= mask;
  r.hi.x *= mask; r.hi.y *= mask; r.hi.z *= mask; r.hi.w *= mask;
  float lf = __shfl_up(r.hi.w, 1);
  float rt = __shfl_down(r.lo.x, 1);
  r.lft = (lane == 0)  ? 0.f : lf;   // pixel -1  -> 0 (image edge)
  r.rgt = (lane == 63) ? 0.f : rt;   // pixel 512 -> 0
}

__device__ __forceinline__ void compute_store(const Row& T, const Row& M,
                                              const Row& B, int* orow) {
  int res[8];
#pragma unroll
  for (int j = 0; j < 8; ++j) {
    float t0 = rget(T, j), t1 = rget(T, j + 1), t2 = rget(T, j + 2);
    float m0 = rget(M, j),                      m2 = rget(M, j + 2);
    float b0 = rget(B, j), b1 = rget(B, j + 1), b2 = rget(B, j + 2);
    float tx = (b0 - t0) + 2.f * (b1 - t1) + (b2 - t2);            // f_x
    float ty = (t2 - t0) + 2.f * (m2 - m0) + (b2 - b0);            // f_y
    float d1 = -2.f * t0 - t1 - m0 + m2 + b1 + 2.f * b2;           // f_tl_br
    float d2 = -t1 - 2.f * t2 + m0 - m2 + 2.f * b0 + b1;           // f_tr_bl
    float e = fabsf(tx) + fabsf(ty) + fabsf(d1) + fabsf(d2);
    res[j] = (e > 0.f) ? 1 : 0;
  }
  *reinterpret_cast<int4*>(orow)     = make_int4(res[0], res[1], res[2], res[3]);
  *reinterpret_cast<int4*>(orow + 4) = make_int4(res[4], res[5], res[6], res[7]);
}

__global__ __launch_bounds__(256, 4) void edgenet_kernel(
    const float* __restrict__ in, int* __restrict__ out) {
  const int lane = threadIdx.x & 63;
  const int wid  = threadIdx.x >> 6;                 // 0..3
  const int b    = blockIdx.x >> 4;                  // image index
  const int y0   = ((blockIdx.x & 15) << 5) + (wid << 3);  // strip start row
  const int px   = lane << 3;                        // first pixel of lane

  const float* img = in + (size_t)b * (IMG_H * IMG_W);
  int* orow = out + ((size_t)b * IMG_H + y0) * IMG_W + px;

  Row s[WSLOTS];
  // prologue: 6 row loads (y0-1 .. y0+4) issued back-to-back, all counted
#pragma unroll
  for (int k = 0; k < WSLOTS; ++k) loadrow(s[k], img, y0 - 1 + k, px);
  finishrow(s[0], y0 - 1, lane);
  finishrow(s[1], y0,     lane);

#pragma unroll
  for (int i = 0; i < R_ROWS; ++i) {
    finishrow(s[(i + 2) % WSLOTS], y0 + i + 1, lane);   // row y0+i+1 ready
    compute_store(s[i % WSLOTS], s[(i + 1) % WSLOTS], s[(i + 2) % WSLOTS],
                  orow + i * IMG_W);
    if (i + 5 <= R_ROWS)                                // rows y0+5 .. y0+8
      loadrow(s[i % WSLOTS], img, y0 + i + 5, px);      // slot's row is dead
  }
}

extern "C" void kernel_launch(void* const* d_in, const int* in_sizes, int n_in,
                              void* d_out, int out_size, void* d_ws, size_t ws_size,
                              hipStream_t stream) {
  const float* lab = (const float*)d_in[0];
  int* out = (int*)d_out;
  // 64 images x 16 blocks per image (block: 4 waves x 8-row full-width strips)
  int blocks = 64 * (IMG_H / (4 * R_ROWS));          // 1024
  edgenet_kernel<<<blocks, 256, 0, stream>>>(lab, out);
}

// Round 8
// 28.500 us; speedup vs baseline: 1.0741x; 1.0741x over previous
//
#include <hip/hip_runtime.h>

// Edgenet: 4-channel fixed 3x3 Sobel-family stencil on [64,1,512,512] f32,
// edge = (sum_c |conv_c|) > 0 ? 1 : 0, output int32 [64,512,512].
//
// Round-8: LDS-staged, copy-like global streams. Rounds 3/6/7 (register
// sliding windows, various depths/widths) all pin at 4.4-4.7 TB/s: the
// fine-grained interleave of dependent loads/shuffles/stores is the last
// difference vs copy (6.3 TB/s) / LayerNorm-class (82%) kernels. Here each
// block stages 18 rows (36 KB LDS) with 9 unconditional back-to-back float4
// loads per thread (fire-and-forget burst), one barrier, then computes from
// LDS. Image-edge rows handled by clamped stage address + wave-uniform 0/1
// mask at LDS read (no branches around loads). Regular int4 stores
// (nontemporal = proven 4x regression). 2048 blocks, 4 blocks/CU.

#define IMG_W 512
#define IMG_H 512
#define TROWS 16              // output rows per block
#define SROWS (TROWS + 2)    // staged rows incl halo

struct Row {
  float4 lo, hi;   // pixels 8l..8l+3, 8l+4..8l+7
  float lft, rgt;  // halo pixels 8l-1, 8l+8
};

__device__ __forceinline__ float rget(const Row& r, int k) {
  switch (k) {   // k is compile-time constant after full unroll
    case 0: return r.lft;
    case 1: return r.lo.x; case 2: return r.lo.y;
    case 3: return r.lo.z; case 4: return r.lo.w;
    case 5: return r.hi.x; case 6: return r.hi.y;
    case 7: return r.hi.z; case 8: return r.hi.w;
    default: return r.rgt;
  }
}

__device__ __forceinline__ void compute_store(const Row& T, const Row& M,
                                              const Row& B, int* orow) {
  int res[8];
#pragma unroll
  for (int j = 0; j < 8; ++j) {
    float t0 = rget(T, j), t1 = rget(T, j + 1), t2 = rget(T, j + 2);
    float m0 = rget(M, j),                      m2 = rget(M, j + 2);
    float b0 = rget(B, j), b1 = rget(B, j + 1), b2 = rget(B, j + 2);
    float tx = (b0 - t0) + 2.f * (b1 - t1) + (b2 - t2);            // f_x
    float ty = (t2 - t0) + 2.f * (m2 - m0) + (b2 - b0);            // f_y
    float d1 = -2.f * t0 - t1 - m0 + m2 + b1 + 2.f * b2;           // f_tl_br
    float d2 = -t1 - 2.f * t2 + m0 - m2 + 2.f * b0 + b1;           // f_tr_bl
    float e = fabsf(tx) + fabsf(ty) + fabsf(d1) + fabsf(d2);
    res[j] = (e > 0.f) ? 1 : 0;
  }
  *reinterpret_cast<int4*>(orow)     = make_int4(res[0], res[1], res[2], res[3]);
  *reinterpret_cast<int4*>(orow + 4) = make_int4(res[4], res[5], res[6], res[7]);
}

__global__ __launch_bounds__(256) void edgenet_kernel(
    const float* __restrict__ in, int* __restrict__ out) {
  __shared__ float lds[SROWS * IMG_W];
  const int tid  = threadIdx.x;
  const int lane = tid & 63;
  const int wid  = tid >> 6;                 // 0..3
  const int b    = blockIdx.x >> 5;          // image index
  const int t    = blockIdx.x & 31;          // tile index
  const int y0   = t << 4;                   // first output row of tile
  const float* img = in + (size_t)b * (IMG_H * IMG_W);

  // ---- stage 18 rows (image rows y0-1 .. y0+16, clamped) ----
  // float4 index space: 18 rows * 128 = 2304 = 9 * 256 loads, all unconditional
#pragma unroll
  for (int k = 0; k < 9; ++k) {
    int idx = tid + (k << 8);                // 0..2303
    int lr  = idx >> 7;                      // LDS row 0..17
    int c   = (idx & 127) << 2;              // float col 0..508
    int gy  = min(max(y0 + lr - 1, 0), IMG_H - 1);
    float4 v = *reinterpret_cast<const float4*>(img + gy * IMG_W + c);
    *reinterpret_cast<float4*>(&lds[lr * IMG_W + c]) = v;
  }
  __syncthreads();

  // ---- compute: wave wid -> output rows y0+4*wid .. y0+4*wid+3 ----
  const int r0 = wid << 2;

  auto ldrow = [&](int lr, Row& r) {
    const float* p = &lds[lr * IMG_W + (lane << 3)];
    float4 lo = *reinterpret_cast<const float4*>(p);
    float4 hi = *reinterpret_cast<const float4*>(p + 4);
    // LDS row lr holds image row y0+lr-1; zero it if outside the image
    float mk = ((unsigned)(y0 + lr - 1) < (unsigned)IMG_H) ? 1.f : 0.f;
    lo.x *= mk; lo.y *= mk; lo.z *= mk; lo.w *= mk;
    hi.x *= mk; hi.y *= mk; hi.z *= mk; hi.w *= mk;
    r.lo = lo; r.hi = hi;
    float lf = __shfl_up(hi.w, 1);
    float rt = __shfl_down(lo.x, 1);
    r.lft = (lane == 0)  ? 0.f : lf;   // pixel -1  -> 0 (image edge)
    r.rgt = (lane == 63) ? 0.f : rt;   // pixel 512 -> 0
  };

  Row s[3];
  ldrow(r0,     s[0]);
  ldrow(r0 + 1, s[1]);
  ldrow(r0 + 2, s[2]);
  int* orow = out + ((size_t)b * IMG_H + y0 + r0) * IMG_W + (lane << 3);
#pragma unroll
  for (int i = 0; i < 4; ++i) {        // full unroll: s[] indices fold to consts
    compute_store(s[i % 3], s[(i + 1) % 3], s[(i + 2) % 3], orow + i * IMG_W);
    if (i < 3) ldrow(r0 + i + 3, s[i % 3]);
  }
}

extern "C" void kernel_launch(void* const* d_in, const int* in_sizes, int n_in,
                              void* d_out, int out_size, void* d_ws, size_t ws_size,
                              hipStream_t stream) {
  const float* lab = (const float*)d_in[0];
  int* out = (int*)d_out;
  // 64 images x 32 tiles (block: 4 waves; 16 output rows per block)
  int blocks = 64 * (IMG_H / TROWS);           // 2048
  edgenet_kernel<<<blocks, 256, 0, stream>>>(lab, out);
}